// Round 6
// baseline (842.734 us; speedup 1.0000x reference)
//
#include <hip/hip_runtime.h>

typedef __attribute__((ext_vector_type(8))) short bf16x8;
typedef __attribute__((ext_vector_type(4))) float f32x4;

#define SL 2048
#define DM 768
#define NCH 32
#define MSPEC 24576   /* 32*768 */
#define MTOT  26880   /* 24576 + 3*768 */

__device__ __forceinline__ short f2bf(float f) {
  unsigned u = __builtin_bit_cast(unsigned, f);
  u = (u + 0x7FFFu + ((u >> 16) & 1u)) >> 16;
  return (short)u;
}

// ---------------- prep kernels ----------------

__global__ __launch_bounds__(256) void k_zero(float4* out) {
  out[blockIdx.x * 256 + threadIdx.x] = float4{0.f, 0.f, 0.f, 0.f};
}

// xT[d][l] = bf16(x[l][d])   (768 x 2048), LDS tiled transpose
__global__ __launch_bounds__(256) void k_prep_xT(const float* __restrict__ x,
                                                 short* __restrict__ xT) {
  __shared__ short tile[64][65];
  const int d0 = blockIdx.x * 64, l0 = blockIdx.y * 64;
  const int t = threadIdx.x;
#pragma unroll
  for (int rr = 0; rr < 16; ++rr) {
    int ll = rr * 4 + (t >> 6), dl = t & 63;
    tile[ll][dl] = f2bf(x[(size_t)(l0 + ll) * DM + d0 + dl]);
  }
  __syncthreads();
#pragma unroll
  for (int rr = 0; rr < 16; ++rr) {
    int dl = rr * 4 + (t >> 6), ll = t & 63;
    xT[(size_t)(d0 + dl) * SL + l0 + ll] = tile[ll][dl];
  }
}

// AR columns of U: U[l][24576 + i*768 + d] = x[l-i][d] (0 if l<i)
__global__ __launch_bounds__(256) void k_prep_ar(const float* __restrict__ x,
                                                 short* __restrict__ U) {
  int id = blockIdx.x * 256 + threadIdx.x;   // over 2048*768
  int l = id / DM, d = id - l * DM;
#pragma unroll
  for (int i = 0; i < 3; ++i) {
    short v = 0;
    if (l >= i) v = f2bf(x[(size_t)(l - i) * DM + d]);
    U[(size_t)l * MTOT + MSPEC + i * DM + d] = v;
  }
}

// Tmat[c][dlag][a][b] = f_c[dlag*128 + a - b]
__global__ __launch_bounds__(256) void k_prep_T(const float* __restrict__ phi,
                                                short* __restrict__ Tmat) {
  int idx = blockIdx.x * 256 + threadIdx.x;  // 32*16*128*128
  int b = idx & 127, a = (idx >> 7) & 127, dlag = (idx >> 14) & 15, c = idx >> 18;
  int j = dlag * 128 + a - b;
  short v = 0;
  if (j >= 0) {
    float p = phi[j * 16 + (c & 15)];
    if (c >= 16 && (j & 1)) p = -p;
    v = f2bf(p);
  }
  Tmat[idx] = v;
}

// McatT[o][m] (768 x 26880): m<24576 -> sigma^(1/4)-scaled M_phi_plus/minus; else M_u
__global__ __launch_bounds__(256) void k_prep_M(const float* __restrict__ Mp,
                                                const float* __restrict__ Mm,
                                                const float* __restrict__ Mu,
                                                const float* __restrict__ sigma,
                                                short* __restrict__ McatT) {
  __shared__ short tile[64][65];
  const int m0 = blockIdx.x * 64, o0 = blockIdx.y * 64;
  const int t = threadIdx.x;
#pragma unroll
  for (int rr = 0; rr < 16; ++rr) {
    int ml = rr * 4 + (t >> 6), ol = t & 63;
    int m = m0 + ml, o = o0 + ol;
    float v;
    if (m < MSPEC) {
      int c = m / DM, d = m - c * DM;
      int k = c & 15;
      float s4 = sqrtf(sqrtf(sigma[k]));
      if (c < 16) v = Mp[((size_t)c * DM + d) * DM + o] * s4;
      else        v = Mm[((size_t)(c - 16) * DM + d) * DM + o] * s4;
    } else {
      int mm = m - MSPEC;
      int i = mm / DM, d = mm - i * DM;
      v = Mu[((size_t)i * DM + d) * DM + o];
    }
    tile[ml][ol] = f2bf(v);
  }
  __syncthreads();
#pragma unroll
  for (int rr = 0; rr < 16; ++rr) {
    int ol = rr * 4 + (t >> 6), ml = t & 63;
    McatT[(size_t)(o0 + ol) * MTOT + m0 + ml] = tile[ml][ol];
  }
}

// ---------------- GEMM 1: block-Toeplitz conv — LDS-free, barrier-free ----------------
__global__ __launch_bounds__(256) void k_gemm1(const short* __restrict__ Tmat,
                                               const short* __restrict__ xT,
                                               short* __restrict__ U) {
  const int wid = blockIdx.x;
  const int slot = wid >> 3;                 // 0..383
  const int c = (wid & 7) * 4 + (slot & 3);  // 4 channels per XCD
  const int dtile = (slot >> 2) % 6;
  const int ib = 15 - (slot >> 2) / 6;       // big (triangular) blocks first
  const int t = threadIdx.x;
  const int lane = t & 63, wave = t >> 6;
  const int wm = (wave >> 1) * 64, wn = (wave & 1) * 64;
  const int lrow = lane & 15, quad = lane >> 4;

  const short* aRow[4];
  const short* bRow[4];
#pragma unroll
  for (int im = 0; im < 4; ++im)
    aRow[im] = Tmat + (((size_t)c * 16) << 14) + (wm + im * 16 + lrow) * 128 + quad * 8;
#pragma unroll
  for (int in = 0; in < 4; ++in)
    bRow[in] = xT + (size_t)(dtile * 128 + wn + in * 16 + lrow) * SL + quad * 8;

  f32x4 acc[4][4] = {};
  bf16x8 a0[4], b0[4], a1[4], b1[4];
  const int nit = 4 * (ib + 1);              // even, >=4

  auto ld = [&](int it, bf16x8* A, bf16x8* B) {
    const int dlag = it >> 2, kk = it & 3;
    const int aOff = dlag * (128 * 128) + kk * 32;
    const int bOff = (ib - dlag) * 128 + kk * 32;
#pragma unroll
    for (int im = 0; im < 4; ++im)
      A[im] = *reinterpret_cast<const bf16x8*>(aRow[im] + aOff);
#pragma unroll
    for (int in = 0; in < 4; ++in)
      B[in] = *reinterpret_cast<const bf16x8*>(bRow[in] + bOff);
  };
  auto mm = [&](bf16x8* A, bf16x8* B) {
#pragma unroll
    for (int im = 0; im < 4; ++im)
#pragma unroll
      for (int in = 0; in < 4; ++in)
        acc[im][in] = __builtin_amdgcn_mfma_f32_16x16x32_bf16(A[im], B[in], acc[im][in], 0, 0, 0);
  };

  // pipeline: nit even => loop exits with a0 = frag(nit-2) unconsumed,
  // a1 = frag(nit-1) unconsumed.
  ld(0, a0, b0);
  ld(1, a1, b1);
  for (int it = 0; it < nit - 2; it += 2) {
    mm(a0, b0);
    ld(it + 2, a0, b0);
    mm(a1, b1);
    if (it + 3 < nit) ld(it + 3, a1, b1);
  }
  mm(a0, b0);
  mm(a1, b1);

  const int l0 = ib * 128, colbase = c * DM + dtile * 128;
#pragma unroll
  for (int im = 0; im < 4; ++im)
#pragma unroll
    for (int in = 0; in < 4; ++in)
#pragma unroll
      for (int r4 = 0; r4 < 4; ++r4) {
        int row = wm + im * 16 + quad * 4 + r4;
        int col = wn + in * 16 + lrow;
        U[(size_t)(l0 + row) * MTOT + colbase + col] = f2bf(acc[im][in][r4]);
      }
}

// ---------------- GEMM 2: projection + AR — LDS-free, barrier-free, split-K=8 ----------------
// 768 blocks = 3/CU (one residency round); kc = wid&7 pins each K-slice to one XCD.
__global__ __launch_bounds__(256) void k_gemm2(const short* __restrict__ U,
                                               const short* __restrict__ McatT,
                                               float* __restrict__ out) {
  const int wid = blockIdx.x;
  const int kc = wid & 7;
  const int slot = wid >> 3;                 // 0..95
  const int otile = slot % 6;
  const int lb = slot / 6;
  const int ns = 105;                        // 105 * 32 = 3360 K per kc (odd!)
  const int t = threadIdx.x;
  const int lane = t & 63, wave = t >> 6;
  const int wm = (wave >> 1) * 64, wn = (wave & 1) * 64;
  const int lrow = lane & 15, quad = lane >> 4;

  const short* aRow[4];
  const short* bRow[4];
#pragma unroll
  for (int im = 0; im < 4; ++im)
    aRow[im] = U + (size_t)(lb * 128 + wm + im * 16 + lrow) * MTOT + kc * 3360 + quad * 8;
#pragma unroll
  for (int in = 0; in < 4; ++in)
    bRow[in] = McatT + (size_t)(otile * 128 + wn + in * 16 + lrow) * MTOT + kc * 3360 + quad * 8;

  f32x4 acc[4][4] = {};
  bf16x8 a0[4], b0[4], a1[4], b1[4];

  auto ld = [&](int s, bf16x8* A, bf16x8* B) {
    const int off = s * 32;
#pragma unroll
    for (int im = 0; im < 4; ++im)
      A[im] = *reinterpret_cast<const bf16x8*>(aRow[im] + off);
#pragma unroll
    for (int in = 0; in < 4; ++in)
      B[in] = *reinterpret_cast<const bf16x8*>(bRow[in] + off);
  };
  auto mm = [&](bf16x8* A, bf16x8* B) {
#pragma unroll
    for (int im = 0; im < 4; ++im)
#pragma unroll
      for (int in = 0; in < 4; ++in)
        acc[im][in] = __builtin_amdgcn_mfma_f32_16x16x32_bf16(A[im], B[in], acc[im][in], 0, 0, 0);
  };

  // Pipeline trace for odd ns=105: loop s=0..102 step 2; at s=102 we do
  // mm(f102), ld(104->a0), mm(f103), no further load. Exit: a0=f104 is the
  // ONLY unconsumed fragment -> exactly one tail mm. (Even ns would leave two.)
  ld(0, a0, b0);
  ld(1, a1, b1);
  for (int s = 0; s < ns - 2; s += 2) {
    mm(a0, b0);
    ld(s + 2, a0, b0);
    mm(a1, b1);
    if (s + 3 < ns) ld(s + 3, a1, b1);
  }
  mm(a0, b0);
  if ((ns & 1) == 0) mm(a1, b1);

  const int l0 = lb * 128, o0 = otile * 128;
#pragma unroll
  for (int im = 0; im < 4; ++im)
#pragma unroll
    for (int in = 0; in < 4; ++in)
#pragma unroll
      for (int r4 = 0; r4 < 4; ++r4) {
        int row = wm + im * 16 + quad * 4 + r4;
        int col = wn + in * 16 + lrow;
        atomicAdd(&out[(size_t)(l0 + row) * DM + o0 + col], acc[im][in][r4]);
      }
}

extern "C" void kernel_launch(void* const* d_in, const int* in_sizes, int n_in,
                              void* d_out, int out_size, void* d_ws, size_t ws_size,
                              hipStream_t stream) {
  (void)in_sizes; (void)n_in; (void)out_size; (void)ws_size;
  const float* x     = (const float*)d_in[0];
  const float* phi   = (const float*)d_in[1];
  const float* sigma = (const float*)d_in[2];
  const float* Mp    = (const float*)d_in[3];
  const float* Mm    = (const float*)d_in[4];
  const float* Mu    = (const float*)d_in[5];
  float* out = (float*)d_out;
  char* ws = (char*)d_ws;

  short* U     = (short*)(ws);                    // 2048*26880*2   = 110,100,480
  short* Tmat  = (short*)(ws + 110100480);        // 32*16*128*128*2 = 16,777,216
  short* xT    = (short*)(ws + 126877696);        // 768*2048*2     = 3,145,728
  short* McatT = (short*)(ws + 130023424);        // 768*26880*2    = 41,287,680

  k_zero<<<dim3(1536), dim3(256), 0, stream>>>((float4*)out);
  k_prep_xT<<<dim3(12, 32), dim3(256), 0, stream>>>(x, xT);
  k_prep_ar<<<dim3(6144), dim3(256), 0, stream>>>(x, U);
  k_prep_T<<<dim3(32768), dim3(256), 0, stream>>>(phi, Tmat);
  k_prep_M<<<dim3(420, 12), dim3(256), 0, stream>>>(Mp, Mm, Mu, sigma, McatT);
  k_gemm1<<<dim3(3072), dim3(256), 0, stream>>>(Tmat, xT, U);
  k_gemm2<<<dim3(768), dim3(256), 0, stream>>>(U, McatT, out);
}

// Round 7
// 444.181 us; speedup vs baseline: 1.8973x; 1.8973x over previous
//
#include <hip/hip_runtime.h>

typedef __attribute__((ext_vector_type(8))) short bf16x8;
typedef __attribute__((ext_vector_type(4))) float f32x4;

#define SL 2048
#define DM 768
#define MSPEC 24576   /* 32*768 */
#define MTOT  26880   /* 24576 + 3*768 */

__device__ __forceinline__ short f2bf(float f) {
  unsigned u = __builtin_bit_cast(unsigned, f);
  u = (u + 0x7FFFu + ((u >> 16) & 1u)) >> 16;
  return (short)u;
}

// async global->LDS, 16B per lane. LDS dest must be wave-uniform base + lane*16.
__device__ __forceinline__ void gload16(const short* g, short* l) {
  __builtin_amdgcn_global_load_lds(
      (const __attribute__((address_space(1))) void*)g,
      (__attribute__((address_space(3))) void*)l, 16, 0, 0);
}

// ---------------- front: zero + xT transpose + Tmat + AR columns (one launch) ----------------
// sections: [0,1536) zero out; [1536,1920) xT; [1920,6016) Tmat; [6016,8320) AR
__global__ __launch_bounds__(256) void k_front(const float* __restrict__ x,
                                               const float* __restrict__ phi,
                                               float* __restrict__ out,
                                               short* __restrict__ xT,
                                               short* __restrict__ Tmat,
                                               short* __restrict__ U) {
  __shared__ short tile[64 * 65];
  const int wid = blockIdx.x;
  const int t = threadIdx.x;

  if (wid < 1536) {                       // ---- zero out (6.3 MB)
    reinterpret_cast<float4*>(out)[(size_t)wid * 256 + t] = float4{0.f, 0.f, 0.f, 0.f};

  } else if (wid < 1920) {                // ---- xT[d][l] = bf16(x[l][d])
    const int b = wid - 1536;
    const int d0 = (b % 12) * 64, l0 = (b / 12) * 64;
#pragma unroll
    for (int rr = 0; rr < 16; ++rr) {
      int ll = rr * 4 + (t >> 6), dl = t & 63;
      tile[ll * 65 + dl] = f2bf(x[(size_t)(l0 + ll) * DM + d0 + dl]);
    }
    __syncthreads();
#pragma unroll
    for (int rr = 0; rr < 16; ++rr) {
      int dl = rr * 4 + (t >> 6), ll = t & 63;
      xT[(size_t)(d0 + dl) * SL + l0 + ll] = tile[ll * 65 + dl];
    }

  } else if (wid < 6016) {                // ---- Tmat[c][dlag][a][b] = f_c[dlag*128+a-b], 8/thread
    int g = (wid - 1920) * 256 + t;       // 0..1048575
    int b8 = g & 15, a = (g >> 4) & 127, dlag = (g >> 11) & 15, c = g >> 15;
    int k = c & 15;
    int jb = dlag * 128 + a - b8 * 8;
    short v[8];
#pragma unroll
    for (int i2 = 0; i2 < 8; ++i2) {
      int j = jb - i2;
      float p = 0.f;
      if (j >= 0) {
        p = phi[j * 16 + k];
        if (c >= 16 && (j & 1)) p = -p;
      }
      v[i2] = f2bf(p);
    }
    *reinterpret_cast<int4*>(Tmat + (size_t)g * 8) = *reinterpret_cast<const int4*>(v);

  } else {                                // ---- AR cols: U[l][MSPEC+i*768+d] = x[l-i][d], 8/thread
    int g = (wid - 6016) * 256 + t;       // 0..589823
    int d8 = g % 96;
    int rest = g / 96;                    // i*2048 + l
    int l = rest & 2047, i = rest >> 11;  // i in 0..2
    int d = d8 * 8;
    short v[8] = {0, 0, 0, 0, 0, 0, 0, 0};
    if (l >= i) {
      const float4* src = reinterpret_cast<const float4*>(x + (size_t)(l - i) * DM + d);
      float4 f0 = src[0], f1 = src[1];
      v[0] = f2bf(f0.x); v[1] = f2bf(f0.y); v[2] = f2bf(f0.z); v[3] = f2bf(f0.w);
      v[4] = f2bf(f1.x); v[5] = f2bf(f1.y); v[6] = f2bf(f1.z); v[7] = f2bf(f1.w);
    }
    *reinterpret_cast<int4*>(U + (size_t)l * MTOT + MSPEC + i * DM + d) =
        *reinterpret_cast<const int4*>(v);
  }
}

// ---------------- mid: gemm1 (blocks 0..3071) + prep_M (blocks 3072..8111) ----------------
// gemm1: block-Toeplitz conv, dbuf global_load_lds, XCD-pinned channels (round-3 proven).
// prep_M: builds McatT, runs concurrently in gemm1's latency bubbles.
__global__ __launch_bounds__(256) void k_mid(const short* __restrict__ Tmat,
                                             const short* __restrict__ xT,
                                             short* __restrict__ U,
                                             const float* __restrict__ Mp,
                                             const float* __restrict__ Mm,
                                             const float* __restrict__ Mu,
                                             const float* __restrict__ sigma,
                                             short* __restrict__ McatT) {
  __shared__ __align__(16) short As[2][128 * 32];
  __shared__ __align__(16) short Bs[2][128 * 32];
  const int wid = blockIdx.x;
  const int t = threadIdx.x;

  if (wid < 3072) {
    // ---------------- gemm1 (verbatim round-3) ----------------
    const int slot = wid >> 3;                 // 0..383
    const int c = (wid & 7) * 4 + (slot & 3);  // 4 channels per XCD
    const int dtile = (slot >> 2) % 6;
    const int ib = 15 - (slot >> 2) / 6;       // big (triangular) blocks first
    const int lane = t & 63, wave = t >> 6;
    const int wm = (wave >> 1) * 64, wn = (wave & 1) * 64;
    const int lrow = lane & 15, quad = lane >> 4;
    const int l4 = lane >> 2, lq = lane & 3;
    const int r0 = wave * 32 + l4;
    const int swz = (lq ^ ((l4 >> 1) & 3)) * 8;
    const int foff = ((quad ^ ((lrow >> 1) & 3)) << 3);

    f32x4 acc[4][4] = {};
    const short* Abase = Tmat + (((size_t)c * 16) << 14) + r0 * 128 + swz;
    const short* Bbase = xT + (size_t)dtile * 128 * SL + (size_t)r0 * SL + swz;
    const int nit = 4 * (ib + 1);

    auto stage = [&](int it, int buf) {
      int dlag = it >> 2, kk = it & 3;
      const short* Ad = Abase + ((size_t)dlag << 14) + kk * 32;
      const short* Bd = Bbase + (ib - dlag) * 128 + kk * 32;
      short* lA = &As[buf][wave * 1024 + lane * 8];
      short* lB = &Bs[buf][wave * 1024 + lane * 8];
      gload16(Ad, lA);
      gload16(Ad + 16 * 128, lA + 512);
      gload16(Bd, lB);
      gload16(Bd + 16 * SL, lB + 512);
    };

    stage(0, 0);
    int cur = 0;
    for (int it = 0; it < nit; ++it) {
      __syncthreads();                      // drains prefetch into buf 'cur'
      if (it + 1 < nit) stage(it + 1, cur ^ 1);
      bf16x8 af[4], bfr[4];
#pragma unroll
      for (int im = 0; im < 4; ++im)
        af[im] = *reinterpret_cast<const bf16x8*>(&As[cur][(wm + im * 16 + lrow) * 32 + foff]);
#pragma unroll
      for (int in = 0; in < 4; ++in)
        bfr[in] = *reinterpret_cast<const bf16x8*>(&Bs[cur][(wn + in * 16 + lrow) * 32 + foff]);
#pragma unroll
      for (int im = 0; im < 4; ++im)
#pragma unroll
        for (int in = 0; in < 4; ++in)
          acc[im][in] = __builtin_amdgcn_mfma_f32_16x16x32_bf16(af[im], bfr[in], acc[im][in], 0, 0, 0);
      cur ^= 1;
    }
    const int l0 = ib * 128, colbase = c * DM + dtile * 128;
#pragma unroll
    for (int im = 0; im < 4; ++im)
#pragma unroll
      for (int in = 0; in < 4; ++in)
#pragma unroll
        for (int r4 = 0; r4 < 4; ++r4) {
          int row = wm + im * 16 + quad * 4 + r4;
          int col = wn + in * 16 + lrow;
          U[(size_t)(l0 + row) * MTOT + colbase + col] = f2bf(acc[im][in][r4]);
        }

  } else {
    // ---------------- prep_M: McatT[o][m], 64x64 tiles (aliases As as scratch) ----------------
    short* tile = &As[0][0];                   // 8192 shorts available >= 64*65
    const int idx = wid - 3072;                // 0..5039
    const int m0 = (idx % 420) * 64, o0 = (idx / 420) * 64;
#pragma unroll
    for (int rr = 0; rr < 16; ++rr) {
      int ml = rr * 4 + (t >> 6), ol = t & 63;
      int m = m0 + ml, o = o0 + ol;
      float v;
      if (m < MSPEC) {
        int c = m / DM, d = m - c * DM;
        int k = c & 15;
        float s4 = sqrtf(sqrtf(sigma[k]));
        if (c < 16) v = Mp[((size_t)c * DM + d) * DM + o] * s4;
        else        v = Mm[((size_t)(c - 16) * DM + d) * DM + o] * s4;
      } else {
        int mm = m - MSPEC;
        int i = mm / DM, d = mm - i * DM;
        v = Mu[((size_t)i * DM + d) * DM + o];
      }
      tile[ml * 65 + ol] = f2bf(v);
    }
    __syncthreads();
#pragma unroll
    for (int rr = 0; rr < 16; ++rr) {
      int ol = rr * 4 + (t >> 6), ml = t & 63;
      McatT[(size_t)(o0 + ol) * MTOT + m0 + ml] = tile[ml * 65 + ol];
    }
  }
}

// ---------------- GEMM 2: projection + AR, split-K=8, dbuf (verbatim round-3) ----------------
__global__ __launch_bounds__(256) void k_gemm2(const short* __restrict__ U,
                                               const short* __restrict__ McatT,
                                               float* __restrict__ out) {
  __shared__ __align__(16) short As[2][128 * 32];
  __shared__ __align__(16) short Bs[2][128 * 32];
  const int wid = blockIdx.x;
  const int kc = wid & 7;
  const int slot = wid >> 3;                 // 0..95
  const int otile = slot % 6;
  const int lb = slot / 6;
  const int t = threadIdx.x;
  const int lane = t & 63, wave = t >> 6;
  const int wm = (wave >> 1) * 64, wn = (wave & 1) * 64;
  const int lrow = lane & 15, quad = lane >> 4;
  const int l4 = lane >> 2, lq = lane & 3;
  const int r0 = wave * 32 + l4;
  const int swz = (lq ^ ((l4 >> 1) & 3)) * 8;
  const int foff = ((quad ^ ((lrow >> 1) & 3)) << 3);

  f32x4 acc[4][4] = {};
  const short* Ab = U + (size_t)lb * 128 * MTOT + kc * 3360 + (size_t)r0 * MTOT + swz;
  const short* Bb = McatT + (size_t)otile * 128 * MTOT + kc * 3360 + (size_t)r0 * MTOT + swz;

  auto stage = [&](int s, int buf) {
    short* lA = &As[buf][wave * 1024 + lane * 8];
    short* lB = &Bs[buf][wave * 1024 + lane * 8];
    gload16(Ab + s * 32, lA);
    gload16(Ab + s * 32 + (size_t)16 * MTOT, lA + 512);
    gload16(Bb + s * 32, lB);
    gload16(Bb + s * 32 + (size_t)16 * MTOT, lB + 512);
  };

  stage(0, 0);
  int cur = 0;
  for (int s = 0; s < 105; ++s) {
    __syncthreads();
    if (s + 1 < 105) stage(s + 1, cur ^ 1);
    bf16x8 af[4], bfr[4];
#pragma unroll
    for (int im = 0; im < 4; ++im)
      af[im] = *reinterpret_cast<const bf16x8*>(&As[cur][(wm + im * 16 + lrow) * 32 + foff]);
#pragma unroll
    for (int in = 0; in < 4; ++in)
      bfr[in] = *reinterpret_cast<const bf16x8*>(&Bs[cur][(wn + in * 16 + lrow) * 32 + foff]);
#pragma unroll
    for (int im = 0; im < 4; ++im)
#pragma unroll
      for (int in = 0; in < 4; ++in)
        acc[im][in] = __builtin_amdgcn_mfma_f32_16x16x32_bf16(af[im], bfr[in], acc[im][in], 0, 0, 0);
    cur ^= 1;
  }
  const int l0 = lb * 128, o0 = otile * 128;
#pragma unroll
  for (int im = 0; im < 4; ++im)
#pragma unroll
    for (int in = 0; in < 4; ++in)
#pragma unroll
      for (int r4 = 0; r4 < 4; ++r4) {
        int row = wm + im * 16 + quad * 4 + r4;
        int col = wn + in * 16 + lrow;
        atomicAdd(&out[(size_t)(l0 + row) * DM + o0 + col], acc[im][in][r4]);
      }
}

extern "C" void kernel_launch(void* const* d_in, const int* in_sizes, int n_in,
                              void* d_out, int out_size, void* d_ws, size_t ws_size,
                              hipStream_t stream) {
  (void)in_sizes; (void)n_in; (void)out_size; (void)ws_size;
  const float* x     = (const float*)d_in[0];
  const float* phi   = (const float*)d_in[1];
  const float* sigma = (const float*)d_in[2];
  const float* Mp    = (const float*)d_in[3];
  const float* Mm    = (const float*)d_in[4];
  const float* Mu    = (const float*)d_in[5];
  float* out = (float*)d_out;
  char* ws = (char*)d_ws;

  short* U     = (short*)(ws);                    // 2048*26880*2   = 110,100,480
  short* Tmat  = (short*)(ws + 110100480);        // 32*16*128*128*2 = 16,777,216
  short* xT    = (short*)(ws + 126877696);        // 768*2048*2     = 3,145,728
  short* McatT = (short*)(ws + 130023424);        // 768*26880*2    = 41,287,680

  k_front<<<dim3(8320), dim3(256), 0, stream>>>(x, phi, out, xT, Tmat, U);
  k_mid<<<dim3(8112), dim3(256), 0, stream>>>(Tmat, xT, U, Mp, Mm, Mu, sigma, McatT);
  k_gemm2<<<dim3(768), dim3(256), 0, stream>>>(U, McatT, out);
}